// Round 8
// baseline (77.012 us; speedup 1.0000x reference)
//
#include <hip/hip_runtime.h>
#include <math.h>

#define N_LAYERS 5
#define NG 20

// ---------------------------------------------------------------------------
// I$-front mitigation (R7, kept — measured best): every CU re-streams kernel
// code from HBM every dispatch (poison-fill evicts L2/L3; I$ misses are
// serial). Touch the code region as DATA at entry (parallel loads populate
// L2), consume at kernel end so the loads fly under the front.
// ---------------------------------------------------------------------------
__device__ __forceinline__ float code_warm_8k() {
    unsigned long long pc;
    asm volatile("s_getpc_b64 %0" : "=s"(pc));
    const unsigned long long base = (pc - 256ULL) & ~63ULL;
    const float* p = (const float*)(base + (unsigned long long)((threadIdx.x & 63) << 6));
    return p[0] + p[1024];          // 2 x 4 KB of code lines
}

// ---------------------------------------------------------------------------
// Pre-kernel (verified R2/R6/R7, byte-identical body to R7): compose the 20
// shared U3 gates + ring CNOTs into one 16x16 complex unitary. 256 threads,
// one amplitude per thread (t = col*16 + row), butterflies via __shfl_xor,
// CNOTs via shuffled selects, layer loop ROLLED (code ~1.5 KB).
// Layout: row j plane-separated: W[j*32+k]=Re, W[j*32+16+k]=Im.
// ---------------------------------------------------------------------------
__global__ __launch_bounds__(256) void compose_W(const float* __restrict__ w,
                                                 float* __restrict__ W) {
    const float warm = code_warm_8k();

    __shared__ float g[NG][8];
    const int t = threadIdx.x;
    if (t < NG) {
        float th = w[t * 3 + 0], ph = w[t * 3 + 1], la = w[t * 3 + 2];
        float st, ct, sl, cl, sp, cp, spl, cpl;
        sincosf(th * 0.5f, &st, &ct);
        sincosf(la, &sl, &cl);
        sincosf(ph, &sp, &cp);
        sincosf(ph + la, &spl, &cpl);
        g[t][0] = ct;        g[t][1] = 0.0f;
        g[t][2] = -cl * st;  g[t][3] = -sl * st;
        g[t][4] = cp * st;   g[t][5] = sp * st;
        g[t][6] = cpl * ct;  g[t][7] = spl * ct;
    }
    __syncthreads();

    const int row = t & 15;   // output basis index (wire0 = bit3)
    const int col = t >> 4;   // input basis column

    float wr = (row == col) ? 1.0f : 0.0f;
    float wi = 0.0f;

#pragma unroll 1
    for (int l = 0; l < N_LAYERS; ++l) {
#pragma unroll
        for (int q = 0; q < 4; ++q) {
            const float* gm = g[l * 4 + q];
            const float m00r = gm[0];
            const float m01r = gm[2], m01i = gm[3];
            const float m10r = gm[4], m10i = gm[5];
            const float m11r = gm[6], m11i = gm[7];
            const int stride = 8 >> q;

            const float pr = __shfl_xor(wr, stride, 64);
            const float pi = __shfl_xor(wi, stride, 64);
            const bool up = (row & stride) != 0;

            const float cAr = up ? m11r : m00r;
            const float cAi = up ? m11i : 0.0f;
            const float cBr = up ? m10r : m01r;
            const float cBi = up ? m10i : m01i;

            const float nr = cAr * wr - cAi * wi + cBr * pr - cBi * pi;
            const float ni = cAr * wi + cAi * wr + cBr * pi + cBi * pr;
            wr = nr; wi = ni;
        }
        // ring CNOTs (0,1)(1,2)(2,3)(3,0): row permutation
#pragma unroll
        for (int e = 0; e < 4; ++e) {
            const int cm = 8 >> e;
            const int tm = 8 >> ((e + 1) & 3);
            const float pr = __shfl_xor(wr, tm, 64);
            const float pi = __shfl_xor(wi, tm, 64);
            if (row & cm) { wr = pr; wi = pi; }
        }
    }

    W[row * 32 + col]      = wr;   // Re plane
    W[row * 32 + 16 + col] = wi;   // Im plane

    asm volatile("" :: "v"(warm));
}

// ---------------------------------------------------------------------------
// Main kernel v8: one sample/thread, j-loop FULLY unrolled (R5: rolling
// regressed on s_load waits), but every FMA shaped as v_fmac_f32 (VOP2, 4 B):
//   acc = fmaf(W_sgpr, v_reg, acc)
// with a PRE-NEGATED nsi[k] = -si[k] register file so the "-wv*si" term
// needs no VOP3 neg-modifier. Matvec code ~10 KB -> ~4.5 KB; the serial
// per-CU I$ front (the dominant qmain cost after R7's warm) halves.
// W delivery stays the load-bearing trick: compile-time-uniform address ->
// s_load -> SGPR operand, zero VALU/DS cost. Per-k FMA order is R2-exact
// (sign flip exact) -> numerics unchanged.
// ---------------------------------------------------------------------------
__global__ __launch_bounds__(256) void qmain(const float* __restrict__ x,
                                             const float* __restrict__ W,
                                             float* __restrict__ out) {
    const float warm = code_warm_8k();

    const int b = blockIdx.x * 256 + threadIdx.x;
    const float4 xv = ((const float4*)x)[b];
    const float xs[4] = {xv.x, xv.y, xv.z, xv.w};

    // encoding columns: [cos(x/2), e^{ix} sin(x/2)]
    float vr[4][2], vi[4][2];
#pragma unroll
    for (int i = 0; i < 4; i++) {
        const float st = __sinf(xs[i] * 0.5f);
        const float ct = __cosf(xs[i] * 0.5f);
        const float sx = __sinf(xs[i]);
        const float cx = __cosf(xs[i]);
        vr[i][0] = ct;      vi[i][0] = 0.0f;
        vr[i][1] = cx * st; vi[i][1] = sx * st;
    }

    // tensor product -> 16 complex amps (wire0 = bit3)
    float w01r[4], w01i[4], w23r[4], w23i[4];
#pragma unroll
    for (int a = 0; a < 2; a++) {
#pragma unroll
        for (int c = 0; c < 2; c++) {
            w01r[a * 2 + c] = vr[0][a] * vr[1][c] - vi[0][a] * vi[1][c];
            w01i[a * 2 + c] = vr[0][a] * vi[1][c] + vi[0][a] * vr[1][c];
            w23r[a * 2 + c] = vr[2][a] * vr[3][c] - vi[2][a] * vi[3][c];
            w23i[a * 2 + c] = vr[2][a] * vi[3][c] + vi[2][a] * vr[3][c];
        }
    }
    float sr[16], si[16], nsi[16];
#pragma unroll
    for (int hi = 0; hi < 4; hi++) {
#pragma unroll
        for (int lo = 0; lo < 4; lo++) {
            const int i = hi * 4 + lo;
            sr[i]  = w01r[hi] * w23r[lo] - w01i[hi] * w23i[lo];
            si[i]  = w01r[hi] * w23i[lo] + w01i[hi] * w23r[lo];
            nsi[i] = -si[i];
        }
    }

    // psi_j = sum_k W[j][k] * psi0_k ; p_j = |psi_j|^2
    float p[16];
#pragma unroll
    for (int j = 0; j < 16; ++j) {
        float prr = 0.0f, pii = 0.0f;
#pragma unroll
        for (int k = 0; k < 16; ++k) {
            const float wr = W[j * 32 + k];        // Re, uniform -> s_load
            const float wv = W[j * 32 + 16 + k];   // Im, uniform -> s_load
            prr = fmaf(wr, sr[k], prr);    // v_fmac (VOP2)
            prr = fmaf(wv, nsi[k], prr);   // v_fmac (VOP2, pre-negated imag)
            pii = fmaf(wr, si[k], pii);    // v_fmac
            pii = fmaf(wv, sr[k], pii);    // v_fmac
        }
        p[j] = fmaf(prr, prr, pii * pii);
    }

    // butterfly signed reduction: bit0=wire3 ... bit3=wire0 (R0/R2-exact)
    const float a0 = p[0] + p[1],   a1 = p[2] + p[3],   a2 = p[4] + p[5],   a3 = p[6] + p[7];
    const float a4 = p[8] + p[9],   a5 = p[10] + p[11], a6 = p[12] + p[13], a7 = p[14] + p[15];
    const float z3 = (p[0] - p[1]) + (p[2] - p[3]) + (p[4] - p[5]) + (p[6] - p[7])
                   + (p[8] - p[9]) + (p[10] - p[11]) + (p[12] - p[13]) + (p[14] - p[15]);
    const float b0 = a0 + a1, b1 = a2 + a3, b2 = a4 + a5, b3 = a6 + a7;
    const float z2 = (a0 - a1) + (a2 - a3) + (a4 - a5) + (a6 - a7);
    const float c0 = b0 + b1, c1 = b2 + b3;
    const float z1 = (b0 - b1) + (b2 - b3);
    const float z0 = c0 - c1;

    ((float4*)out)[b] = make_float4(z0, z1, z2, z3);

    asm volatile("" :: "v"(warm));
}

extern "C" void kernel_launch(void* const* d_in, const int* in_sizes, int n_in,
                              void* d_out, int out_size, void* d_ws, size_t ws_size,
                              hipStream_t stream) {
    const float* x = (const float*)d_in[0];   // [B,4] fp32
    const float* w = (const float*)d_in[1];   // [5,4,3] fp32
    float* out = (float*)d_out;               // [B,4] fp32
    float* W = (float*)d_ws;                  // 16*32 floats = 2 KB (plane-separated rows)
    const int b = in_sizes[0] / 4;

    compose_W<<<1, 256, 0, stream>>>(w, W);
    qmain<<<b / 256, 256, 0, stream>>>(x, W, out);
}